// Round 3
// baseline (94.853 us; speedup 1.0000x reference)
//
#include <hip/hip_runtime.h>
#include <hip/hip_bf16.h>

// ---------------------------------------------------------------------------
// Fused MLP+LSTM for B=131072 rows, v3.
// 1024-thread blocks (16 waves), 512 rows/block, grid = 256 = 1 block/CU.
// Each block converts the 4 big weight layers (fp32, L2/L3-hot) directly into
// its own LDS (144 KB) in MFMA fragment order. Small layers + biases prepped
// once into global ws by a tiny prep kernel. Operand-swapped MFMA chain:
// D = W * act^T keeps the batch row at lane&15 across all layers.
// ---------------------------------------------------------------------------

typedef __bf16 bf16x8 __attribute__((ext_vector_type(8)));
typedef float  f32x4  __attribute__((ext_vector_type(4)));

#define MFMA16(A, B, C) __builtin_amdgcn_mfma_f32_16x16x32_bf16((A), (B), (C), 0, 0, 0)

// fragment-element offsets (bf16 elems). [0, LDS_ELEMS) lives in per-block LDS;
// [LDS_ELEMS, WTOT) lives in global ws (prepped once).
#define WOFF_FC1    0
#define WOFF_FC1A_H 32768
#define WOFF_FC1B   49152
#define WOFF_FC1C   65536
#define LDS_ELEMS   73728          // 147456 B = 144 KB
#define WOFF_FC1A_W 73728
#define WOFF_FC2    81920
#define WOFF_FC3    83968
#define WOFF_WIH    84992
#define WOFF_WHH    89088
#define WOFF_FC4    93184
#define WTOT        94208
// bias offsets (floats, after bf16 region in ws)
#define BOFF_FC1  0
#define BOFF_FC1A 128
#define BOFF_FC1B 256
#define BOFF_FC1C 384
#define BOFF_FC2  448
#define BOFF_FC3  480
#define BOFF_LSTM 512
#define BOFF_FC4  640
#define BTOT      672

// ---------------------------------------------------------------------------
// Fragment mapping (same as v1/v2, verified passing):
//   elem index rel -> j = rel&7, lane = (rel>>3)&63, fs = rel>>9, s = fs%ns,
//   t = fs/ns, gq = lane>>4, n = 16t + (lane&15),
//   k = perm ? 16*(2s + (j>>2)) + 4*gq + (j&3) : 32*s + 8*gq + j
// ---------------------------------------------------------------------------
__device__ __forceinline__ void conv_frag(int rel, const float* __restrict__ src,
                                          __bf16* __restrict__ dst,
                                          int ns, int Krow, int kbase, int klim, int perm) {
    int j    = rel & 7;
    int lane = (rel >> 3) & 63;
    int fs   = rel >> 9;
    int s    = fs % ns;
    int t    = fs / ns;
    int gq   = lane >> 4;
    int n    = 16 * t + (lane & 15);
    int k    = perm ? (16 * (2 * s + (j >> 2)) + 4 * gq + (j & 3))
                    : (32 * s + 8 * gq + j);
    float v  = (k < klim) ? src[n * Krow + kbase + k] : 0.f;
    dst[rel] = (__bf16)v;
}

// 8 consecutive elems (one thread, one ds_write_b128) for full-K layers
__device__ __forceinline__ bf16x8 conv8(int rel8, const float* __restrict__ src,
                                        int ns, int Krow, int perm) {
    int lane = (rel8 >> 3) & 63;
    int fs   = rel8 >> 9;
    int s    = fs % ns;
    int t    = fs / ns;
    int gq   = lane >> 4;
    int n    = 16 * t + (lane & 15);
    const float* rowp = src + n * Krow;
    f32x4 a, b;
    if (perm) {                     // j=0..3 -> k0..k0+3 ; j=4..7 -> k0+16..k0+19
        int k0 = 32 * s + 4 * gq;
        a = *(const f32x4*)(rowp + k0);
        b = *(const f32x4*)(rowp + k0 + 16);
    } else {                        // j=0..7 -> contiguous 8
        int k0 = 32 * s + 8 * gq;
        a = *(const f32x4*)(rowp + k0);
        b = *(const f32x4*)(rowp + k0 + 4);
    }
    bf16x8 r;
    r[0] = (__bf16)a[0]; r[1] = (__bf16)a[1]; r[2] = (__bf16)a[2]; r[3] = (__bf16)a[3];
    r[4] = (__bf16)b[0]; r[5] = (__bf16)b[1]; r[6] = (__bf16)b[2]; r[7] = (__bf16)b[3];
    return r;
}

// ---------------------------------------------------------------------------
// Tiny prep: small layers + biases only (21152 elems)
// ---------------------------------------------------------------------------
__global__ void prep_kernel(const float* __restrict__ fc1aw, const float* __restrict__ fc1b,
                            const float* __restrict__ fc1ab, const float* __restrict__ fc1bb,
                            const float* __restrict__ wgame, const float* __restrict__ fc1cw,
                            const float* __restrict__ fc1cb, const float* __restrict__ fc2w,
                            const float* __restrict__ fc2b,  const float* __restrict__ fc3w,
                            const float* __restrict__ fc3b,  const float* __restrict__ wih,
                            const float* __restrict__ whh,   const float* __restrict__ bih,
                            const float* __restrict__ bhh,   const float* __restrict__ fc4w,
                            const float* __restrict__ fc4b,
                            __bf16* __restrict__ wsw, float* __restrict__ wsb) {
    int idx = blockIdx.x * 256 + threadIdx.x + LDS_ELEMS;
    if (idx < WTOT) {
        if      (idx < WOFF_FC2)  conv_frag(idx - WOFF_FC1A_W, fc1aw, wsw + WOFF_FC1A_W, 2, 164, 128, 36, 0);
        else if (idx < WOFF_FC3)  conv_frag(idx - WOFF_FC2,    fc2w,  wsw + WOFF_FC2,    2,  64,   0, 64, 1);
        else if (idx < WOFF_WIH)  conv_frag(idx - WOFF_FC3,    fc3w,  wsw + WOFF_FC3,    1,  32,   0, 32, 1);
        else if (idx < WOFF_WHH)  conv_frag(idx - WOFF_WIH,    wih,   wsw + WOFF_WIH,    1,  32,   0, 32, 1);
        else if (idx < WOFF_FC4)  conv_frag(idx - WOFF_WHH,    whh,   wsw + WOFF_WHH,    1,  32,   0, 32, 0);
        else                      conv_frag(idx - WOFF_FC4,    fc4w,  wsw + WOFF_FC4,    1,  32,   0, 32, 1);
    } else if (idx < WTOT + BTOT) {
        int bi = idx - WTOT;
        float v;
        if      (bi < 128) v = fc1b[bi];
        else if (bi < 256) v = fc1ab[bi - 128];
        else if (bi < 384) v = fc1bb[bi - 256];
        else if (bi < 448) {            // fold fc1c_w[:,128:140] @ w_game into bias
            int n = bi - 384;
            v = fc1cb[n];
            for (int q = 0; q < 12; ++q) v += fc1cw[n * 140 + 128 + q] * wgame[q];
        }
        else if (bi < 480) v = fc2b[bi - 448];
        else if (bi < 512) v = fc3b[bi - 480];
        else if (bi < 640) { int n = bi - 512; v = bih[n] + bhh[n]; }   // fused LSTM bias
        else               v = fc4b[bi - 640];
        wsb[bi] = v;
    }
}

// ---------------------------------------------------------------------------
// Helpers
// ---------------------------------------------------------------------------
__device__ __forceinline__ bf16x8 ld8f(const float* __restrict__ p) {
    f32x4 a = *(const f32x4*)p;
    f32x4 b = *(const f32x4*)(p + 4);
    bf16x8 r;
    r[0] = (__bf16)a[0]; r[1] = (__bf16)a[1]; r[2] = (__bf16)a[2]; r[3] = (__bf16)a[3];
    r[4] = (__bf16)b[0]; r[5] = (__bf16)b[1]; r[6] = (__bf16)b[2]; r[7] = (__bf16)b[3];
    return r;
}

__device__ __forceinline__ bf16x8 ld4f_masked(const float* __restrict__ p, bool on) {
    f32x4 v = {0.f, 0.f, 0.f, 0.f};
    if (on) v = *(const f32x4*)p;
    bf16x8 r;
    r[0] = (__bf16)v[0]; r[1] = (__bf16)v[1]; r[2] = (__bf16)v[2]; r[3] = (__bf16)v[3];
    r[4] = (__bf16)0.f;  r[5] = (__bf16)0.f;  r[6] = (__bf16)0.f;  r[7] = (__bf16)0.f;
    return r;
}

__device__ __forceinline__ bf16x8 packrelu(const f32x4* a, int s) {
    bf16x8 r;
#pragma unroll
    for (int j = 0; j < 8; ++j) {
        float v = a[2 * s + (j >> 2)][j & 3];
        r[j] = (__bf16)fmaxf(v, 0.f);
    }
    return r;
}

__device__ __forceinline__ float sigm(float v)  { return 1.f / (1.f + __expf(-v)); }
__device__ __forceinline__ float tanh_(float v) { return 1.f - 2.f / (1.f + __expf(2.f * v)); }

// ---------------------------------------------------------------------------
// Fused main kernel: 16 waves/block, 32 rows/wave, 512 rows/block
// ---------------------------------------------------------------------------
__global__ __launch_bounds__(1024, 4) void fused_mlp_lstm(
        const float* __restrict__ x,  const float* __restrict__ w,
        const float* __restrict__ h0, const float* __restrict__ c0,
        const float* __restrict__ fc5w, const float* __restrict__ fc5b,
        const float* __restrict__ fc1w, const float* __restrict__ fc1aw,
        const float* __restrict__ fc1bw, const float* __restrict__ fc1cw,
        const __bf16* __restrict__ wsw, const float* __restrict__ wsb,
        float* __restrict__ out) {
    __shared__ __align__(16) __bf16 slds[LDS_ELEMS];   // 144 KB

    const int tid     = threadIdx.x;
    const int lane    = tid & 63;
    const int wv      = blockIdx.x * 16 + (tid >> 6);
    const int gq      = lane >> 4;
    const int mr      = lane & 15;
    const int rowbase = wv * 32;
    const int row0    = rowbase + mr;
    const int row1    = rowbase + 16 + mr;

    // ---- convert big weight layers fp32 -> bf16 fragments, straight to LDS
    // 9 iters x 1024 threads x 8 elems = 73728 elems. Linear ds_write_b128,
    // conflict-free. Sources are L2/L3-hot (every block reads the same 377KB).
#pragma unroll 3
    for (int i = 0; i < 9; ++i) {
        int rel8 = (i * 1024 + tid) * 8;
        bf16x8 v;
        if      (rel8 < WOFF_FC1A_H) v = conv8(rel8 - WOFF_FC1,    fc1w,  8, 256, 0);
        else if (rel8 < WOFF_FC1B)   v = conv8(rel8 - WOFF_FC1A_H, fc1aw, 4, 164, 1);
        else if (rel8 < WOFF_FC1C)   v = conv8(rel8 - WOFF_FC1B,   fc1bw, 4, 128, 1);
        else                         v = conv8(rel8 - WOFF_FC1C,   fc1cw, 4, 140, 1);
        *(bf16x8*)(slds + rel8) = v;
    }

    // ---- preload x-tile / w-tile / h0 to bf16 regs (overlaps staging) -----
    bf16x8 xf[2][8];
#pragma unroll
    for (int s = 0; s < 8; ++s) {
        xf[0][s] = ld8f(x + row0 * 256 + 32 * s + 8 * gq);
        xf[1][s] = ld8f(x + row1 * 256 + 32 * s + 8 * gq);
    }
    bf16x8 wxa0 = ld8f(w + row0 * 36 + 8 * gq);
    bf16x8 wxb0 = ld8f(w + row1 * 36 + 8 * gq);
    bf16x8 wxa1 = ld4f_masked(w + row0 * 36 + 32, gq == 0);
    bf16x8 wxb1 = ld4f_masked(w + row1 * 36 + 32, gq == 0);
    bf16x8 h0fa = ld8f(h0 + row0 * 32 + 8 * gq);
    bf16x8 h0fb = ld8f(h0 + row1 * 32 + 8 * gq);

    __syncthreads();

    const bf16x8* Wfc1  = (const bf16x8*)(slds + WOFF_FC1);
    const bf16x8* Wf1aH = (const bf16x8*)(slds + WOFF_FC1A_H);
    const bf16x8* Wfc1b = (const bf16x8*)(slds + WOFF_FC1B);
    const bf16x8* Wfc1c = (const bf16x8*)(slds + WOFF_FC1C);
    const bf16x8* Wf1aW = (const bf16x8*)(wsw + WOFF_FC1A_W);
    const bf16x8* Wfc2  = (const bf16x8*)(wsw + WOFF_FC2);
    const bf16x8* Wfc3  = (const bf16x8*)(wsw + WOFF_FC3);
    const bf16x8* Wwih  = (const bf16x8*)(wsw + WOFF_WIH);
    const bf16x8* Wwhh  = (const bf16x8*)(wsw + WOFF_WHH);
    const bf16x8* Wfc4  = (const bf16x8*)(wsw + WOFF_FC4);

    // ---- L1: x[256] -> h1[128] -------------------------------------------
    f32x4 acc1[2][8];
#pragma unroll
    for (int t = 0; t < 8; ++t) {
        f32x4 bv = *(const f32x4*)(wsb + BOFF_FC1 + 16 * t + 4 * gq);
        acc1[0][t] = bv; acc1[1][t] = bv;
    }
#pragma unroll
    for (int s = 0; s < 8; ++s) {
#pragma unroll
        for (int t = 0; t < 8; ++t) {
            bf16x8 wf = Wfc1[(t * 8 + s) * 64 + lane];
            acc1[0][t] = MFMA16(wf, xf[0][s], acc1[0][t]);
            acc1[1][t] = MFMA16(wf, xf[1][s], acc1[1][t]);
        }
    }
    bf16x8 h1f[2][4];
#pragma unroll
    for (int s = 0; s < 4; ++s) { h1f[0][s] = packrelu(acc1[0], s); h1f[1][s] = packrelu(acc1[1], s); }

    // ---- L1a: [h1, w] (128+36) -> h2[128] --------------------------------
    f32x4 acc2[2][8];
#pragma unroll
    for (int t = 0; t < 8; ++t) {
        f32x4 bv = *(const f32x4*)(wsb + BOFF_FC1A + 16 * t + 4 * gq);
        acc2[0][t] = bv; acc2[1][t] = bv;
    }
#pragma unroll
    for (int s = 0; s < 4; ++s) {
#pragma unroll
        for (int t = 0; t < 8; ++t) {
            bf16x8 wf = Wf1aH[(t * 4 + s) * 64 + lane];
            acc2[0][t] = MFMA16(wf, h1f[0][s], acc2[0][t]);
            acc2[1][t] = MFMA16(wf, h1f[1][s], acc2[1][t]);
        }
    }
#pragma unroll
    for (int t = 0; t < 8; ++t) {
        bf16x8 wf0 = Wf1aW[(t * 2 + 0) * 64 + lane];
        bf16x8 wf1 = Wf1aW[(t * 2 + 1) * 64 + lane];
        acc2[0][t] = MFMA16(wf0, wxa0, acc2[0][t]);
        acc2[1][t] = MFMA16(wf0, wxb0, acc2[1][t]);
        acc2[0][t] = MFMA16(wf1, wxa1, acc2[0][t]);
        acc2[1][t] = MFMA16(wf1, wxb1, acc2[1][t]);
    }
    // preload c0 (fp32, used at LSTM) while compute continues
    f32x4 c0r[2][2];
#pragma unroll
    for (int t2 = 0; t2 < 2; ++t2) {
        c0r[0][t2] = *(const f32x4*)(c0 + row0 * 32 + 16 * t2 + 4 * gq);
        c0r[1][t2] = *(const f32x4*)(c0 + row1 * 32 + 16 * t2 + 4 * gq);
    }

    bf16x8 h2f[2][4];
#pragma unroll
    for (int s = 0; s < 4; ++s) { h2f[0][s] = packrelu(acc2[0], s); h2f[1][s] = packrelu(acc2[1], s); }

    // ---- L1b: h2[128] -> h3[128] -----------------------------------------
    f32x4 acc3[2][8];
#pragma unroll
    for (int t = 0; t < 8; ++t) {
        f32x4 bv = *(const f32x4*)(wsb + BOFF_FC1B + 16 * t + 4 * gq);
        acc3[0][t] = bv; acc3[1][t] = bv;
    }
#pragma unroll
    for (int s = 0; s < 4; ++s) {
#pragma unroll
        for (int t = 0; t < 8; ++t) {
            bf16x8 wf = Wfc1b[(t * 4 + s) * 64 + lane];
            acc3[0][t] = MFMA16(wf, h2f[0][s], acc3[0][t]);
            acc3[1][t] = MFMA16(wf, h2f[1][s], acc3[1][t]);
        }
    }
    bf16x8 h3f[2][4];
#pragma unroll
    for (int s = 0; s < 4; ++s) { h3f[0][s] = packrelu(acc3[0], s); h3f[1][s] = packrelu(acc3[1], s); }

    // ---- L1c: [h3, w_game] -> h4[64]  (w_game folded into bias) ----------
    f32x4 acc4[2][4];
#pragma unroll
    for (int t = 0; t < 4; ++t) {
        f32x4 bv = *(const f32x4*)(wsb + BOFF_FC1C + 16 * t + 4 * gq);
        acc4[0][t] = bv; acc4[1][t] = bv;
    }
#pragma unroll
    for (int s = 0; s < 4; ++s) {
#pragma unroll
        for (int t = 0; t < 4; ++t) {
            bf16x8 wf = Wfc1c[(t * 4 + s) * 64 + lane];
            acc4[0][t] = MFMA16(wf, h3f[0][s], acc4[0][t]);
            acc4[1][t] = MFMA16(wf, h3f[1][s], acc4[1][t]);
        }
    }
    bf16x8 h4f[2][2];
#pragma unroll
    for (int s = 0; s < 2; ++s) { h4f[0][s] = packrelu(acc4[0], s); h4f[1][s] = packrelu(acc4[1], s); }

    // ---- L2: h4[64] -> h5[32] --------------------------------------------
    f32x4 acc5[2][2];
#pragma unroll
    for (int t = 0; t < 2; ++t) {
        f32x4 bv = *(const f32x4*)(wsb + BOFF_FC2 + 16 * t + 4 * gq);
        acc5[0][t] = bv; acc5[1][t] = bv;
    }
#pragma unroll
    for (int s = 0; s < 2; ++s) {
#pragma unroll
        for (int t = 0; t < 2; ++t) {
            bf16x8 wf = Wfc2[(t * 2 + s) * 64 + lane];
            acc5[0][t] = MFMA16(wf, h4f[0][s], acc5[0][t]);
            acc5[1][t] = MFMA16(wf, h4f[1][s], acc5[1][t]);
        }
    }
    bf16x8 h5f[2] = { packrelu(acc5[0], 0), packrelu(acc5[1], 0) };

    // ---- L3: h5[32] -> h6[32] --------------------------------------------
    f32x4 acc6[2][2];
#pragma unroll
    for (int t = 0; t < 2; ++t) {
        f32x4 bv = *(const f32x4*)(wsb + BOFF_FC3 + 16 * t + 4 * gq);
        acc6[0][t] = bv; acc6[1][t] = bv;
    }
#pragma unroll
    for (int t = 0; t < 2; ++t) {
        bf16x8 wf = Wfc3[t * 64 + lane];
        acc6[0][t] = MFMA16(wf, h5f[0], acc6[0][t]);
        acc6[1][t] = MFMA16(wf, h5f[1], acc6[1][t]);
    }
    bf16x8 h6f[2] = { packrelu(acc6[0], 0), packrelu(acc6[1], 0) };

    // ---- LSTM gates ------------------------------------------------------
    f32x4 accg[2][8];
#pragma unroll
    for (int t = 0; t < 8; ++t) {
        f32x4 bv = *(const f32x4*)(wsb + BOFF_LSTM + 16 * t + 4 * gq);
        accg[0][t] = bv; accg[1][t] = bv;
    }
#pragma unroll
    for (int t = 0; t < 8; ++t) {
        bf16x8 wf = Wwih[t * 64 + lane];
        accg[0][t] = MFMA16(wf, h6f[0], accg[0][t]);
        accg[1][t] = MFMA16(wf, h6f[1], accg[1][t]);
    }
#pragma unroll
    for (int t = 0; t < 8; ++t) {
        bf16x8 wf = Wwhh[t * 64 + lane];
        accg[0][t] = MFMA16(wf, h0fa, accg[0][t]);
        accg[1][t] = MFMA16(wf, h0fb, accg[1][t]);
    }
    float hn[2][8];
#pragma unroll
    for (int m = 0; m < 2; ++m) {
#pragma unroll
        for (int t2 = 0; t2 < 2; ++t2) {
            f32x4 cc = c0r[m][t2];
#pragma unroll
            for (int r = 0; r < 4; ++r) {
                float ig = accg[m][t2][r];
                float fg = accg[m][2 + t2][r];
                float gg = accg[m][4 + t2][r];
                float og = accg[m][6 + t2][r];
                float cn = sigm(fg) * cc[r] + sigm(ig) * tanh_(gg);
                hn[m][t2 * 4 + r] = sigm(og) * tanh_(cn);
            }
        }
    }
    bf16x8 hnf[2];
#pragma unroll
    for (int m = 0; m < 2; ++m)
#pragma unroll
        for (int j = 0; j < 8; ++j) hnf[m][j] = (__bf16)hn[m][j];

    // ---- L4: h_new[32] -> o1[32] -----------------------------------------
    f32x4 acco[2][2];
#pragma unroll
    for (int t = 0; t < 2; ++t) {
        f32x4 bv = *(const f32x4*)(wsb + BOFF_FC4 + 16 * t + 4 * gq);
        acco[0][t] = bv; acco[1][t] = bv;
    }
#pragma unroll
    for (int t = 0; t < 2; ++t) {
        bf16x8 wf = Wfc4[t * 64 + lane];
        acco[0][t] = MFMA16(wf, hnf[0], acco[0][t]);
        acco[1][t] = MFMA16(wf, hnf[1], acco[1][t]);
    }

    // ---- L5 + sigmoid ----------------------------------------------------
    f32x4 w5a = *(const f32x4*)(fc5w + 4 * gq);
    f32x4 w5b = *(const f32x4*)(fc5w + 16 + 4 * gq);
    float b5  = fc5b[0];
    float res[2];
#pragma unroll
    for (int m = 0; m < 2; ++m) {
        float p = 0.f;
#pragma unroll
        for (int r = 0; r < 4; ++r) {
            p += fmaxf(acco[m][0][r], 0.f) * w5a[r];
            p += fmaxf(acco[m][1][r], 0.f) * w5b[r];
        }
        p += __shfl_xor(p, 16);
        p += __shfl_xor(p, 32);
        res[m] = sigm(p + b5);
    }
    if (lane < 16) {
        out[rowbase + lane]      = res[0];
        out[rowbase + 16 + lane] = res[1];
    }
}

// ---------------------------------------------------------------------------
extern "C" void kernel_launch(void* const* d_in, const int* in_sizes, int n_in,
                              void* d_out, int out_size, void* d_ws, size_t ws_size,
                              hipStream_t stream) {
    const float* x     = (const float*)d_in[0];
    const float* w     = (const float*)d_in[1];
    const float* h0    = (const float*)d_in[2];
    const float* c0    = (const float*)d_in[3];
    const float* fc1w  = (const float*)d_in[4];
    const float* fc1b  = (const float*)d_in[5];
    const float* fc1aw = (const float*)d_in[6];
    const float* fc1ab = (const float*)d_in[7];
    const float* fc1bw = (const float*)d_in[8];
    const float* fc1bb = (const float*)d_in[9];
    const float* wgame = (const float*)d_in[10];
    const float* fc1cw = (const float*)d_in[11];
    const float* fc1cb = (const float*)d_in[12];
    const float* fc2w  = (const float*)d_in[13];
    const float* fc2b  = (const float*)d_in[14];
    const float* fc3w  = (const float*)d_in[15];
    const float* fc3b  = (const float*)d_in[16];
    const float* wih   = (const float*)d_in[17];
    const float* whh   = (const float*)d_in[18];
    const float* bih   = (const float*)d_in[19];
    const float* bhh   = (const float*)d_in[20];
    const float* fc4w  = (const float*)d_in[21];
    const float* fc4b  = (const float*)d_in[22];
    const float* fc5w  = (const float*)d_in[23];
    const float* fc5b  = (const float*)d_in[24];

    __bf16* wsw = (__bf16*)d_ws;
    float*  wsb = (float*)((char*)d_ws + WTOT * sizeof(__bf16));
    (void)ws_size; (void)n_in; (void)out_size;

    const int Btot = in_sizes[0] / 256;   // 131072 rows

    prep_kernel<<<((WTOT - LDS_ELEMS) + BTOT + 255) / 256, 256, 0, stream>>>(
        fc1aw, fc1b, fc1ab, fc1bb, wgame, fc1cw, fc1cb,
        fc2w, fc2b, fc3w, fc3b, wih, whh, bih, bhh, fc4w, fc4b, wsw, wsb);

    fused_mlp_lstm<<<Btot / 512, 1024, 0, stream>>>(
        x, w, h0, c0, fc5w, fc5b, fc1w, fc1aw, fc1bw, fc1cw,
        wsw, wsb, (float*)d_out);
}

// Round 4
// 68.214 us; speedup vs baseline: 1.3905x; 1.3905x over previous
//
#include <hip/hip_runtime.h>
#include <hip/hip_bf16.h>

// ---------------------------------------------------------------------------
// Fused MLP+LSTM for B=131072 rows, v4.
// 512-thread blocks (8 waves), 256 rows/block, 80 KB LDS -> 2 blocks/CU
// (4 waves/SIMD). LDS holds mid-chain layers FC1A_H+FC1B+FC1C (dependency-
// critical); FC1 weights stream from prepped bf16 ws (L2-hot, no upstream
// dep -> latency overlapped). All fp32->bf16 conversion done once in prep.
// Operand-swapped MFMA chain: D = W*act^T keeps batch row at lane&15.
// ---------------------------------------------------------------------------

typedef __bf16 bf16x8 __attribute__((ext_vector_type(8)));
typedef float  f32x4  __attribute__((ext_vector_type(4)));
typedef int    i32x4  __attribute__((ext_vector_type(4)));

#define MFMA16(A, B, C) __builtin_amdgcn_mfma_f32_16x16x32_bf16((A), (B), (C), 0, 0, 0)

// fragment-element offsets (bf16 elems). [0, LDS_ELEMS) staged to LDS.
#define WOFF_FC1A_H 0
#define WOFF_FC1B   16384
#define WOFF_FC1C   32768
#define LDS_ELEMS   40960          // 81920 B = 80 KB -> 2 blocks/CU
#define WOFF_FC1    40960
#define WOFF_FC1A_W 73728
#define WOFF_FC2    81920
#define WOFF_FC3    83968
#define WOFF_WIH    84992
#define WOFF_WHH    89088
#define WOFF_FC4    93184
#define WTOT        94208
// bias offsets (floats, after bf16 region in ws)
#define BOFF_FC1  0
#define BOFF_FC1A 128
#define BOFF_FC1B 256
#define BOFF_FC1C 384
#define BOFF_FC2  448
#define BOFF_FC3  480
#define BOFF_LSTM 512
#define BOFF_FC4  640
#define BTOT      672

// ---------------------------------------------------------------------------
// Fragment mapping (verified in v1/v2):
//   rel -> j = rel&7, lane = (rel>>3)&63, fs = rel>>9, s = fs%ns, t = fs/ns,
//   gq = lane>>4, n = 16t + (lane&15),
//   k = perm ? 16*(2s + (j>>2)) + 4*gq + (j&3) : 32*s + 8*gq + j
// ---------------------------------------------------------------------------
__device__ __forceinline__ void conv_frag(int rel, const float* __restrict__ src,
                                          __bf16* __restrict__ dst,
                                          int ns, int Krow, int kbase, int klim, int perm) {
    int j    = rel & 7;
    int lane = (rel >> 3) & 63;
    int fs   = rel >> 9;
    int s    = fs % ns;
    int t    = fs / ns;
    int gq   = lane >> 4;
    int n    = 16 * t + (lane & 15);
    int k    = perm ? (16 * (2 * s + (j >> 2)) + 4 * gq + (j & 3))
                    : (32 * s + 8 * gq + j);
    float v  = (k < klim) ? src[n * Krow + kbase + k] : 0.f;
    dst[rel] = (__bf16)v;
}

// ---------------------------------------------------------------------------
// Prep: full fp32 -> bf16 fragment conversion + bias folding (once).
// ---------------------------------------------------------------------------
__global__ void prep_kernel(const float* __restrict__ fc1w,  const float* __restrict__ fc1b,
                            const float* __restrict__ fc1aw, const float* __restrict__ fc1ab,
                            const float* __restrict__ fc1bw, const float* __restrict__ fc1bb,
                            const float* __restrict__ wgame, const float* __restrict__ fc1cw,
                            const float* __restrict__ fc1cb, const float* __restrict__ fc2w,
                            const float* __restrict__ fc2b,  const float* __restrict__ fc3w,
                            const float* __restrict__ fc3b,  const float* __restrict__ wih,
                            const float* __restrict__ whh,   const float* __restrict__ bih,
                            const float* __restrict__ bhh,   const float* __restrict__ fc4w,
                            const float* __restrict__ fc4b,
                            __bf16* __restrict__ wsw, float* __restrict__ wsb) {
    int idx = blockIdx.x * 256 + threadIdx.x;
    if (idx < WTOT) {
        if      (idx < WOFF_FC1B)   conv_frag(idx - WOFF_FC1A_H, fc1aw, wsw + WOFF_FC1A_H, 4, 164,   0, 128, 1);
        else if (idx < WOFF_FC1C)   conv_frag(idx - WOFF_FC1B,   fc1bw, wsw + WOFF_FC1B,   4, 128,   0, 128, 1);
        else if (idx < WOFF_FC1)    conv_frag(idx - WOFF_FC1C,   fc1cw, wsw + WOFF_FC1C,   4, 140,   0, 128, 1);
        else if (idx < WOFF_FC1A_W) conv_frag(idx - WOFF_FC1,    fc1w,  wsw + WOFF_FC1,    8, 256,   0, 256, 0);
        else if (idx < WOFF_FC2)    conv_frag(idx - WOFF_FC1A_W, fc1aw, wsw + WOFF_FC1A_W, 2, 164, 128,  36, 0);
        else if (idx < WOFF_FC3)    conv_frag(idx - WOFF_FC2,    fc2w,  wsw + WOFF_FC2,    2,  64,   0,  64, 1);
        else if (idx < WOFF_WIH)    conv_frag(idx - WOFF_FC3,    fc3w,  wsw + WOFF_FC3,    1,  32,   0,  32, 1);
        else if (idx < WOFF_WHH)    conv_frag(idx - WOFF_WIH,    wih,   wsw + WOFF_WIH,    1,  32,   0,  32, 1);
        else if (idx < WOFF_FC4)    conv_frag(idx - WOFF_WHH,    whh,   wsw + WOFF_WHH,    1,  32,   0,  32, 0);
        else                        conv_frag(idx - WOFF_FC4,    fc4w,  wsw + WOFF_FC4,    1,  32,   0,  32, 1);
    } else if (idx < WTOT + BTOT) {
        int bi = idx - WTOT;
        float v;
        if      (bi < 128) v = fc1b[bi];
        else if (bi < 256) v = fc1ab[bi - 128];
        else if (bi < 384) v = fc1bb[bi - 256];
        else if (bi < 448) {            // fold fc1c_w[:,128:140] @ w_game into bias
            int n = bi - 384;
            v = fc1cb[n];
            for (int q = 0; q < 12; ++q) v += fc1cw[n * 140 + 128 + q] * wgame[q];
        }
        else if (bi < 480) v = fc2b[bi - 448];
        else if (bi < 512) v = fc3b[bi - 480];
        else if (bi < 640) { int n = bi - 512; v = bih[n] + bhh[n]; }   // fused LSTM bias
        else               v = fc4b[bi - 640];
        wsb[bi] = v;
    }
}

// ---------------------------------------------------------------------------
// Helpers
// ---------------------------------------------------------------------------
__device__ __forceinline__ bf16x8 ld8f(const float* __restrict__ p) {
    f32x4 a = *(const f32x4*)p;
    f32x4 b = *(const f32x4*)(p + 4);
    bf16x8 r;
    r[0] = (__bf16)a[0]; r[1] = (__bf16)a[1]; r[2] = (__bf16)a[2]; r[3] = (__bf16)a[3];
    r[4] = (__bf16)b[0]; r[5] = (__bf16)b[1]; r[6] = (__bf16)b[2]; r[7] = (__bf16)b[3];
    return r;
}

__device__ __forceinline__ bf16x8 ld4f_masked(const float* __restrict__ p, bool on) {
    f32x4 v = {0.f, 0.f, 0.f, 0.f};
    if (on) v = *(const f32x4*)p;
    bf16x8 r;
    r[0] = (__bf16)v[0]; r[1] = (__bf16)v[1]; r[2] = (__bf16)v[2]; r[3] = (__bf16)v[3];
    r[4] = (__bf16)0.f;  r[5] = (__bf16)0.f;  r[6] = (__bf16)0.f;  r[7] = (__bf16)0.f;
    return r;
}

__device__ __forceinline__ bf16x8 packrelu(const f32x4* a, int s) {
    bf16x8 r;
#pragma unroll
    for (int j = 0; j < 8; ++j) {
        float v = a[2 * s + (j >> 2)][j & 3];
        r[j] = (__bf16)fmaxf(v, 0.f);
    }
    return r;
}

__device__ __forceinline__ float sigm(float v)  { return 1.f / (1.f + __expf(-v)); }
__device__ __forceinline__ float tanh_(float v) { return 1.f - 2.f / (1.f + __expf(2.f * v)); }

// ---------------------------------------------------------------------------
// Fused main kernel: 8 waves/block, 32 rows/wave, 256 rows/block
// ---------------------------------------------------------------------------
__global__ __launch_bounds__(512, 4) void fused_mlp_lstm(
        const float* __restrict__ x,  const float* __restrict__ w,
        const float* __restrict__ h0, const float* __restrict__ c0,
        const float* __restrict__ fc5w, const float* __restrict__ fc5b,
        const __bf16* __restrict__ wsw, const float* __restrict__ wsb,
        float* __restrict__ out) {
    __shared__ __align__(16) __bf16 slds[LDS_ELEMS];   // 80 KB

    const int tid     = threadIdx.x;
    const int lane    = tid & 63;
    const int wv      = blockIdx.x * 8 + (tid >> 6);
    const int gq      = lane >> 4;
    const int mr      = lane & 15;
    const int rowbase = wv * 32;
    const int row0    = rowbase + mr;
    const int row1    = rowbase + 16 + mr;

    // ---- stage mid-chain weight layers to LDS (10 x 16B per thread) -------
    {
        const i32x4* gs = (const i32x4*)wsw;
        i32x4*       sd = (i32x4*)slds;
#pragma unroll
        for (int i = 0; i < 10; ++i) sd[i * 512 + tid] = gs[i * 512 + tid];
    }

    const bf16x8* Gfc1  = (const bf16x8*)(wsw + WOFF_FC1);
    const bf16x8* Wf1aH = (const bf16x8*)(slds + WOFF_FC1A_H);
    const bf16x8* Wfc1b = (const bf16x8*)(slds + WOFF_FC1B);
    const bf16x8* Wfc1c = (const bf16x8*)(slds + WOFF_FC1C);
    const bf16x8* Wf1aW = (const bf16x8*)(wsw + WOFF_FC1A_W);
    const bf16x8* Wfc2  = (const bf16x8*)(wsw + WOFF_FC2);
    const bf16x8* Wfc3  = (const bf16x8*)(wsw + WOFF_FC3);
    const bf16x8* Wwih  = (const bf16x8*)(wsw + WOFF_WIH);
    const bf16x8* Wwhh  = (const bf16x8*)(wsw + WOFF_WHH);
    const bf16x8* Wfc4  = (const bf16x8*)(wsw + WOFF_FC4);

    // ---- L1: x[256] -> h1[128]  (FC1 weights streamed from global/L2) -----
    f32x4 acc1[2][8];
#pragma unroll
    for (int t = 0; t < 8; ++t) {
        f32x4 bv = *(const f32x4*)(wsb + BOFF_FC1 + 16 * t + 4 * gq);
        acc1[0][t] = bv; acc1[1][t] = bv;
    }
#pragma unroll
    for (int s = 0; s < 8; ++s) {
        bf16x8 xa = ld8f(x + row0 * 256 + 32 * s + 8 * gq);
        bf16x8 xb = ld8f(x + row1 * 256 + 32 * s + 8 * gq);
#pragma unroll
        for (int t = 0; t < 8; ++t) {
            bf16x8 wf = Gfc1[(t * 8 + s) * 64 + lane];
            acc1[0][t] = MFMA16(wf, xa, acc1[0][t]);
            acc1[1][t] = MFMA16(wf, xb, acc1[1][t]);
        }
    }

    __syncthreads();   // LDS staging complete (overlapped with L1 above)

    bf16x8 h1f[2][4];
#pragma unroll
    for (int s = 0; s < 4; ++s) { h1f[0][s] = packrelu(acc1[0], s); h1f[1][s] = packrelu(acc1[1], s); }

    // ---- L1a: [h1, w] (128+36) -> h2[128] --------------------------------
    f32x4 acc2[2][8];
#pragma unroll
    for (int t = 0; t < 8; ++t) {
        f32x4 bv = *(const f32x4*)(wsb + BOFF_FC1A + 16 * t + 4 * gq);
        acc2[0][t] = bv; acc2[1][t] = bv;
    }
#pragma unroll
    for (int s = 0; s < 4; ++s) {
#pragma unroll
        for (int t = 0; t < 8; ++t) {
            bf16x8 wf = Wf1aH[(t * 4 + s) * 64 + lane];
            acc2[0][t] = MFMA16(wf, h1f[0][s], acc2[0][t]);
            acc2[1][t] = MFMA16(wf, h1f[1][s], acc2[1][t]);
        }
    }
    {
        bf16x8 wxa0 = ld8f(w + row0 * 36 + 8 * gq);
        bf16x8 wxb0 = ld8f(w + row1 * 36 + 8 * gq);
        bf16x8 wxa1 = ld4f_masked(w + row0 * 36 + 32, gq == 0);
        bf16x8 wxb1 = ld4f_masked(w + row1 * 36 + 32, gq == 0);
#pragma unroll
        for (int t = 0; t < 8; ++t) {
            bf16x8 wf0 = Wf1aW[(t * 2 + 0) * 64 + lane];
            bf16x8 wf1 = Wf1aW[(t * 2 + 1) * 64 + lane];
            acc2[0][t] = MFMA16(wf0, wxa0, acc2[0][t]);
            acc2[1][t] = MFMA16(wf0, wxb0, acc2[1][t]);
            acc2[0][t] = MFMA16(wf1, wxa1, acc2[0][t]);
            acc2[1][t] = MFMA16(wf1, wxb1, acc2[1][t]);
        }
    }
    bf16x8 h2f[2][4];
#pragma unroll
    for (int s = 0; s < 4; ++s) { h2f[0][s] = packrelu(acc2[0], s); h2f[1][s] = packrelu(acc2[1], s); }

    // ---- L1b: h2[128] -> h3[128] -----------------------------------------
    f32x4 acc3[2][8];
#pragma unroll
    for (int t = 0; t < 8; ++t) {
        f32x4 bv = *(const f32x4*)(wsb + BOFF_FC1B + 16 * t + 4 * gq);
        acc3[0][t] = bv; acc3[1][t] = bv;
    }
#pragma unroll
    for (int s = 0; s < 4; ++s) {
#pragma unroll
        for (int t = 0; t < 8; ++t) {
            bf16x8 wf = Wfc1b[(t * 4 + s) * 64 + lane];
            acc3[0][t] = MFMA16(wf, h2f[0][s], acc3[0][t]);
            acc3[1][t] = MFMA16(wf, h2f[1][s], acc3[1][t]);
        }
    }
    bf16x8 h3f[2][4];
#pragma unroll
    for (int s = 0; s < 4; ++s) { h3f[0][s] = packrelu(acc3[0], s); h3f[1][s] = packrelu(acc3[1], s); }

    // ---- L1c: [h3, w_game] -> h4[64]  (w_game folded into bias) ----------
    f32x4 acc4[2][4];
#pragma unroll
    for (int t = 0; t < 4; ++t) {
        f32x4 bv = *(const f32x4*)(wsb + BOFF_FC1C + 16 * t + 4 * gq);
        acc4[0][t] = bv; acc4[1][t] = bv;
    }
#pragma unroll
    for (int s = 0; s < 4; ++s) {
#pragma unroll
        for (int t = 0; t < 4; ++t) {
            bf16x8 wf = Wfc1c[(t * 4 + s) * 64 + lane];
            acc4[0][t] = MFMA16(wf, h3f[0][s], acc4[0][t]);
            acc4[1][t] = MFMA16(wf, h3f[1][s], acc4[1][t]);
        }
    }
    bf16x8 h4f[2][2];
#pragma unroll
    for (int s = 0; s < 2; ++s) { h4f[0][s] = packrelu(acc4[0], s); h4f[1][s] = packrelu(acc4[1], s); }

    // ---- L2: h4[64] -> h5[32] --------------------------------------------
    f32x4 acc5[2][2];
#pragma unroll
    for (int t = 0; t < 2; ++t) {
        f32x4 bv = *(const f32x4*)(wsb + BOFF_FC2 + 16 * t + 4 * gq);
        acc5[0][t] = bv; acc5[1][t] = bv;
    }
#pragma unroll
    for (int s = 0; s < 2; ++s) {
#pragma unroll
        for (int t = 0; t < 2; ++t) {
            bf16x8 wf = Wfc2[(t * 2 + s) * 64 + lane];
            acc5[0][t] = MFMA16(wf, h4f[0][s], acc5[0][t]);
            acc5[1][t] = MFMA16(wf, h4f[1][s], acc5[1][t]);
        }
    }
    bf16x8 h5f[2] = { packrelu(acc5[0], 0), packrelu(acc5[1], 0) };

    // ---- L3: h5[32] -> h6[32] --------------------------------------------
    f32x4 acc6[2][2];
#pragma unroll
    for (int t = 0; t < 2; ++t) {
        f32x4 bv = *(const f32x4*)(wsb + BOFF_FC3 + 16 * t + 4 * gq);
        acc6[0][t] = bv; acc6[1][t] = bv;
    }
#pragma unroll
    for (int t = 0; t < 2; ++t) {
        bf16x8 wf = Wfc3[t * 64 + lane];
        acc6[0][t] = MFMA16(wf, h5f[0], acc6[0][t]);
        acc6[1][t] = MFMA16(wf, h5f[1], acc6[1][t]);
    }
    bf16x8 h6f[2] = { packrelu(acc6[0], 0), packrelu(acc6[1], 0) };

    // ---- LSTM gates ------------------------------------------------------
    f32x4 accg[2][8];
#pragma unroll
    for (int t = 0; t < 8; ++t) {
        f32x4 bv = *(const f32x4*)(wsb + BOFF_LSTM + 16 * t + 4 * gq);
        accg[0][t] = bv; accg[1][t] = bv;
    }
#pragma unroll
    for (int t = 0; t < 8; ++t) {
        bf16x8 wf = Wwih[t * 64 + lane];
        accg[0][t] = MFMA16(wf, h6f[0], accg[0][t]);
        accg[1][t] = MFMA16(wf, h6f[1], accg[1][t]);
    }
    {
        bf16x8 h0fa = ld8f(h0 + row0 * 32 + 8 * gq);
        bf16x8 h0fb = ld8f(h0 + row1 * 32 + 8 * gq);
#pragma unroll
        for (int t = 0; t < 8; ++t) {
            bf16x8 wf = Wwhh[t * 64 + lane];
            accg[0][t] = MFMA16(wf, h0fa, accg[0][t]);
            accg[1][t] = MFMA16(wf, h0fb, accg[1][t]);
        }
    }
    float hn[2][8];
#pragma unroll
    for (int m = 0; m < 2; ++m) {
        const int row = (m == 0) ? row0 : row1;
#pragma unroll
        for (int t2 = 0; t2 < 2; ++t2) {
            f32x4 cc = *(const f32x4*)(c0 + row * 32 + 16 * t2 + 4 * gq);
#pragma unroll
            for (int r = 0; r < 4; ++r) {
                float ig = accg[m][t2][r];
                float fg = accg[m][2 + t2][r];
                float gg = accg[m][4 + t2][r];
                float og = accg[m][6 + t2][r];
                float cn = sigm(fg) * cc[r] + sigm(ig) * tanh_(gg);
                hn[m][t2 * 4 + r] = sigm(og) * tanh_(cn);
            }
        }
    }
    bf16x8 hnf[2];
#pragma unroll
    for (int m = 0; m < 2; ++m)
#pragma unroll
        for (int j = 0; j < 8; ++j) hnf[m][j] = (__bf16)hn[m][j];

    // ---- L4: h_new[32] -> o1[32] -----------------------------------------
    f32x4 acco[2][2];
#pragma unroll
    for (int t = 0; t < 2; ++t) {
        f32x4 bv = *(const f32x4*)(wsb + BOFF_FC4 + 16 * t + 4 * gq);
        acco[0][t] = bv; acco[1][t] = bv;
    }
#pragma unroll
    for (int t = 0; t < 2; ++t) {
        bf16x8 wf = Wfc4[t * 64 + lane];
        acco[0][t] = MFMA16(wf, hnf[0], acco[0][t]);
        acco[1][t] = MFMA16(wf, hnf[1], acco[1][t]);
    }

    // ---- L5 + sigmoid ----------------------------------------------------
    f32x4 w5a = *(const f32x4*)(fc5w + 4 * gq);
    f32x4 w5b = *(const f32x4*)(fc5w + 16 + 4 * gq);
    float b5  = fc5b[0];
    float res[2];
#pragma unroll
    for (int m = 0; m < 2; ++m) {
        float p = 0.f;
#pragma unroll
        for (int r = 0; r < 4; ++r) {
            p += fmaxf(acco[m][0][r], 0.f) * w5a[r];
            p += fmaxf(acco[m][1][r], 0.f) * w5b[r];
        }
        p += __shfl_xor(p, 16);
        p += __shfl_xor(p, 32);
        res[m] = sigm(p + b5);
    }
    if (lane < 16) {
        out[rowbase + lane]      = res[0];
        out[rowbase + 16 + lane] = res[1];
    }
}

// ---------------------------------------------------------------------------
extern "C" void kernel_launch(void* const* d_in, const int* in_sizes, int n_in,
                              void* d_out, int out_size, void* d_ws, size_t ws_size,
                              hipStream_t stream) {
    const float* x     = (const float*)d_in[0];
    const float* w     = (const float*)d_in[1];
    const float* h0    = (const float*)d_in[2];
    const float* c0    = (const float*)d_in[3];
    const float* fc1w  = (const float*)d_in[4];
    const float* fc1b  = (const float*)d_in[5];
    const float* fc1aw = (const float*)d_in[6];
    const float* fc1ab = (const float*)d_in[7];
    const float* fc1bw = (const float*)d_in[8];
    const float* fc1bb = (const float*)d_in[9];
    const float* wgame = (const float*)d_in[10];
    const float* fc1cw = (const float*)d_in[11];
    const float* fc1cb = (const float*)d_in[12];
    const float* fc2w  = (const float*)d_in[13];
    const float* fc2b  = (const float*)d_in[14];
    const float* fc3w  = (const float*)d_in[15];
    const float* fc3b  = (const float*)d_in[16];
    const float* wih   = (const float*)d_in[17];
    const float* whh   = (const float*)d_in[18];
    const float* bih   = (const float*)d_in[19];
    const float* bhh   = (const float*)d_in[20];
    const float* fc4w  = (const float*)d_in[21];
    const float* fc4b  = (const float*)d_in[22];
    const float* fc5w  = (const float*)d_in[23];
    const float* fc5b  = (const float*)d_in[24];

    __bf16* wsw = (__bf16*)d_ws;
    float*  wsb = (float*)((char*)d_ws + WTOT * sizeof(__bf16));
    (void)ws_size; (void)n_in; (void)out_size;

    const int Btot = in_sizes[0] / 256;   // 131072 rows

    prep_kernel<<<(WTOT + BTOT + 255) / 256, 256, 0, stream>>>(
        fc1w, fc1b, fc1aw, fc1ab, fc1bw, fc1bb, wgame, fc1cw, fc1cb,
        fc2w, fc2b, fc3w, fc3b, wih, whh, bih, bhh, fc4w, fc4b, wsw, wsb);

    fused_mlp_lstm<<<Btot / 256, 512, 0, stream>>>(
        x, w, h0, c0, fc5w, fc5b, wsw, wsb, (float*)d_out);
}

// Round 6
// 62.660 us; speedup vs baseline: 1.5138x; 1.0886x over previous
//
#include <hip/hip_runtime.h>
#include <hip/hip_bf16.h>

// ---------------------------------------------------------------------------
// Fused MLP+LSTM for B=131072 rows, v5 (resubmit — infra failure last round).
// 1024-thread blocks (16 waves, 4 waves/SIMD via __launch_bounds__(1024,4),
// VGPR cap 128), grid = 256 = exactly 1 block/CU. All four big weight layers
// (144 KB bf16 fragments, prepped once) staged to LDS. Register pressure held
// under the 128-cap by splitting the t-loop of the 128-wide layers into two
// halves (acc[2][4] = 32 regs per half instead of acc[2][8] = 64).
// Operand-swapped MFMA chain: D = W*act^T keeps batch row at lane&15.
// ---------------------------------------------------------------------------

typedef __bf16 bf16x8 __attribute__((ext_vector_type(8)));
typedef float  f32x4  __attribute__((ext_vector_type(4)));
typedef int    i32x4  __attribute__((ext_vector_type(4)));

#define MFMA16(A, B, C) __builtin_amdgcn_mfma_f32_16x16x32_bf16((A), (B), (C), 0, 0, 0)

// fragment-element offsets (bf16 elems). [0, LDS_ELEMS) staged to LDS.
#define WOFF_FC1    0
#define WOFF_FC1A_H 32768
#define WOFF_FC1B   49152
#define WOFF_FC1C   65536
#define LDS_ELEMS   73728          // 147456 B = 144 KB
#define WOFF_FC1A_W 73728
#define WOFF_FC2    81920
#define WOFF_FC3    83968
#define WOFF_WIH    84992
#define WOFF_WHH    89088
#define WOFF_FC4    93184
#define WTOT        94208
// bias offsets (floats, after bf16 region in ws)
#define BOFF_FC1  0
#define BOFF_FC1A 128
#define BOFF_FC1B 256
#define BOFF_FC1C 384
#define BOFF_FC2  448
#define BOFF_FC3  480
#define BOFF_LSTM 512
#define BOFF_FC4  640
#define BTOT      672

// ---------------------------------------------------------------------------
// Fragment mapping (verified since v1):
//   rel -> j = rel&7, lane = (rel>>3)&63, fs = rel>>9, s = fs%ns, t = fs/ns,
//   gq = lane>>4, n = 16t + (lane&15),
//   k = perm ? 16*(2s + (j>>2)) + 4*gq + (j&3) : 32*s + 8*gq + j
// ---------------------------------------------------------------------------
__device__ __forceinline__ void conv_frag(int rel, const float* __restrict__ src,
                                          __bf16* __restrict__ dst,
                                          int ns, int Krow, int kbase, int klim, int perm) {
    int j    = rel & 7;
    int lane = (rel >> 3) & 63;
    int fs   = rel >> 9;
    int s    = fs % ns;
    int t    = fs / ns;
    int gq   = lane >> 4;
    int n    = 16 * t + (lane & 15);
    int k    = perm ? (16 * (2 * s + (j >> 2)) + 4 * gq + (j & 3))
                    : (32 * s + 8 * gq + j);
    float v  = (k < klim) ? src[n * Krow + kbase + k] : 0.f;
    dst[rel] = (__bf16)v;
}

// ---------------------------------------------------------------------------
// Prep: full fp32 -> bf16 fragment conversion + bias folding (runs once).
// ---------------------------------------------------------------------------
__global__ void prep_kernel(const float* __restrict__ fc1w,  const float* __restrict__ fc1b,
                            const float* __restrict__ fc1aw, const float* __restrict__ fc1ab,
                            const float* __restrict__ fc1bw, const float* __restrict__ fc1bb,
                            const float* __restrict__ wgame, const float* __restrict__ fc1cw,
                            const float* __restrict__ fc1cb, const float* __restrict__ fc2w,
                            const float* __restrict__ fc2b,  const float* __restrict__ fc3w,
                            const float* __restrict__ fc3b,  const float* __restrict__ wih,
                            const float* __restrict__ whh,   const float* __restrict__ bih,
                            const float* __restrict__ bhh,   const float* __restrict__ fc4w,
                            const float* __restrict__ fc4b,
                            __bf16* __restrict__ wsw, float* __restrict__ wsb) {
    int idx = blockIdx.x * 256 + threadIdx.x;
    if (idx < WTOT) {
        if      (idx < WOFF_FC1A_H) conv_frag(idx - WOFF_FC1,    fc1w,  wsw + WOFF_FC1,    8, 256,   0, 256, 0);
        else if (idx < WOFF_FC1B)   conv_frag(idx - WOFF_FC1A_H, fc1aw, wsw + WOFF_FC1A_H, 4, 164,   0, 128, 1);
        else if (idx < WOFF_FC1C)   conv_frag(idx - WOFF_FC1B,   fc1bw, wsw + WOFF_FC1B,   4, 128,   0, 128, 1);
        else if (idx < WOFF_FC1A_W) conv_frag(idx - WOFF_FC1C,   fc1cw, wsw + WOFF_FC1C,   4, 140,   0, 128, 1);
        else if (idx < WOFF_FC2)    conv_frag(idx - WOFF_FC1A_W, fc1aw, wsw + WOFF_FC1A_W, 2, 164, 128,  36, 0);
        else if (idx < WOFF_FC3)    conv_frag(idx - WOFF_FC2,    fc2w,  wsw + WOFF_FC2,    2,  64,   0,  64, 1);
        else if (idx < WOFF_WIH)    conv_frag(idx - WOFF_FC3,    fc3w,  wsw + WOFF_FC3,    1,  32,   0,  32, 1);
        else if (idx < WOFF_WHH)    conv_frag(idx - WOFF_WIH,    wih,   wsw + WOFF_WIH,    1,  32,   0,  32, 1);
        else if (idx < WOFF_FC4)    conv_frag(idx - WOFF_WHH,    whh,   wsw + WOFF_WHH,    1,  32,   0,  32, 0);
        else                        conv_frag(idx - WOFF_FC4,    fc4w,  wsw + WOFF_FC4,    1,  32,   0,  32, 1);
    } else if (idx < WTOT + BTOT) {
        int bi = idx - WTOT;
        float v;
        if      (bi < 128) v = fc1b[bi];
        else if (bi < 256) v = fc1ab[bi - 128];
        else if (bi < 384) v = fc1bb[bi - 256];
        else if (bi < 448) {            // fold fc1c_w[:,128:140] @ w_game into bias
            int n = bi - 384;
            v = fc1cb[n];
            for (int q = 0; q < 12; ++q) v += fc1cw[n * 140 + 128 + q] * wgame[q];
        }
        else if (bi < 480) v = fc2b[bi - 448];
        else if (bi < 512) v = fc3b[bi - 480];
        else if (bi < 640) { int n = bi - 512; v = bih[n] + bhh[n]; }   // fused LSTM bias
        else               v = fc4b[bi - 640];
        wsb[bi] = v;
    }
}

// ---------------------------------------------------------------------------
// Helpers
// ---------------------------------------------------------------------------
__device__ __forceinline__ bf16x8 ld8f(const float* __restrict__ p) {
    f32x4 a = *(const f32x4*)p;
    f32x4 b = *(const f32x4*)(p + 4);
    bf16x8 r;
    r[0] = (__bf16)a[0]; r[1] = (__bf16)a[1]; r[2] = (__bf16)a[2]; r[3] = (__bf16)a[3];
    r[4] = (__bf16)b[0]; r[5] = (__bf16)b[1]; r[6] = (__bf16)b[2]; r[7] = (__bf16)b[3];
    return r;
}

__device__ __forceinline__ bf16x8 ld4f_masked(const float* __restrict__ p, bool on) {
    f32x4 v = {0.f, 0.f, 0.f, 0.f};
    if (on) v = *(const f32x4*)p;
    bf16x8 r;
    r[0] = (__bf16)v[0]; r[1] = (__bf16)v[1]; r[2] = (__bf16)v[2]; r[3] = (__bf16)v[3];
    r[4] = (__bf16)0.f;  r[5] = (__bf16)0.f;  r[6] = (__bf16)0.f;  r[7] = (__bf16)0.f;
    return r;
}

// pack acc[2s],acc[2s+1] (n = 16t+4g+r) into next-layer B-frag, with relu
__device__ __forceinline__ bf16x8 packrelu(const f32x4* a, int s) {
    bf16x8 r;
#pragma unroll
    for (int j = 0; j < 8; ++j) {
        float v = a[2 * s + (j >> 2)][j & 3];
        r[j] = (__bf16)fmaxf(v, 0.f);
    }
    return r;
}

__device__ __forceinline__ float sigm(float v)  { return 1.f / (1.f + __expf(-v)); }
__device__ __forceinline__ float tanh_(float v) { return 1.f - 2.f / (1.f + __expf(2.f * v)); }

// ---------------------------------------------------------------------------
// Fused main kernel: 16 waves/block, 32 rows/wave, 512 rows/block
// ---------------------------------------------------------------------------
__global__ __launch_bounds__(1024, 4) void fused_mlp_lstm(
        const float* __restrict__ x,  const float* __restrict__ w,
        const float* __restrict__ h0, const float* __restrict__ c0,
        const float* __restrict__ fc5w, const float* __restrict__ fc5b,
        const __bf16* __restrict__ wsw, const float* __restrict__ wsb,
        float* __restrict__ out) {
    __shared__ __align__(16) __bf16 slds[LDS_ELEMS];   // 144 KB

    const int tid     = threadIdx.x;
    const int lane    = tid & 63;
    const int wv      = blockIdx.x * 16 + (tid >> 6);
    const int gq      = lane >> 4;
    const int mr      = lane & 15;
    const int rowbase = wv * 32;
    const int row0    = rowbase + mr;
    const int row1    = rowbase + 16 + mr;

    // ---- stage all big weight layers to LDS (9 x 16B per thread) ----------
    {
        const i32x4* gs = (const i32x4*)wsw;
        i32x4*       sd = (i32x4*)slds;
#pragma unroll
        for (int i = 0; i < 9; ++i) sd[i * 1024 + tid] = gs[i * 1024 + tid];
    }
    __syncthreads();

    const bf16x8* Wfc1  = (const bf16x8*)(slds + WOFF_FC1);
    const bf16x8* Wf1aH = (const bf16x8*)(slds + WOFF_FC1A_H);
    const bf16x8* Wfc1b = (const bf16x8*)(slds + WOFF_FC1B);
    const bf16x8* Wfc1c = (const bf16x8*)(slds + WOFF_FC1C);
    const bf16x8* Wf1aW = (const bf16x8*)(wsw + WOFF_FC1A_W);
    const bf16x8* Wfc2  = (const bf16x8*)(wsw + WOFF_FC2);
    const bf16x8* Wfc3  = (const bf16x8*)(wsw + WOFF_FC3);
    const bf16x8* Wwih  = (const bf16x8*)(wsw + WOFF_WIH);
    const bf16x8* Wwhh  = (const bf16x8*)(wsw + WOFF_WHH);
    const bf16x8* Wfc4  = (const bf16x8*)(wsw + WOFF_FC4);

    // ---- L1: x[256] -> h1[128]  (full t, acc = 64 regs, x transient) ------
    bf16x8 h1f[2][4];
    {
        f32x4 acc1[2][8];
#pragma unroll
        for (int t = 0; t < 8; ++t) {
            f32x4 bv = *(const f32x4*)(wsb + BOFF_FC1 + 16 * t + 4 * gq);
            acc1[0][t] = bv; acc1[1][t] = bv;
        }
#pragma unroll
        for (int s = 0; s < 8; ++s) {
            bf16x8 xa = ld8f(x + row0 * 256 + 32 * s + 8 * gq);
            bf16x8 xb = ld8f(x + row1 * 256 + 32 * s + 8 * gq);
#pragma unroll
            for (int t = 0; t < 8; ++t) {
                bf16x8 wf = Wfc1[(t * 8 + s) * 64 + lane];
                acc1[0][t] = MFMA16(wf, xa, acc1[0][t]);
                acc1[1][t] = MFMA16(wf, xb, acc1[1][t]);
            }
        }
#pragma unroll
        for (int s = 0; s < 4; ++s) { h1f[0][s] = packrelu(acc1[0], s); h1f[1][s] = packrelu(acc1[1], s); }
    }

    // ---- L1a: [h1, w] (128+36) -> h2[128]  (t split into two halves) ------
    bf16x8 h2f[2][4];
#pragma unroll
    for (int th = 0; th < 2; ++th) {
        f32x4 acc2[2][4];
#pragma unroll
        for (int tt = 0; tt < 4; ++tt) {
            f32x4 bv = *(const f32x4*)(wsb + BOFF_FC1A + 16 * (4 * th + tt) + 4 * gq);
            acc2[0][tt] = bv; acc2[1][tt] = bv;
        }
#pragma unroll
        for (int s = 0; s < 4; ++s) {
#pragma unroll
            for (int tt = 0; tt < 4; ++tt) {
                bf16x8 wf = Wf1aH[((4 * th + tt) * 4 + s) * 64 + lane];
                acc2[0][tt] = MFMA16(wf, h1f[0][s], acc2[0][tt]);
                acc2[1][tt] = MFMA16(wf, h1f[1][s], acc2[1][tt]);
            }
        }
        {   // w-concat part (k 128..163); re-loaded per half, L1-hot 2nd time
            bf16x8 wxa0 = ld8f(w + row0 * 36 + 8 * gq);
            bf16x8 wxb0 = ld8f(w + row1 * 36 + 8 * gq);
            bf16x8 wxa1 = ld4f_masked(w + row0 * 36 + 32, gq == 0);
            bf16x8 wxb1 = ld4f_masked(w + row1 * 36 + 32, gq == 0);
#pragma unroll
            for (int tt = 0; tt < 4; ++tt) {
                int t = 4 * th + tt;
                bf16x8 wf0 = Wf1aW[(t * 2 + 0) * 64 + lane];
                bf16x8 wf1 = Wf1aW[(t * 2 + 1) * 64 + lane];
                acc2[0][tt] = MFMA16(wf0, wxa0, acc2[0][tt]);
                acc2[1][tt] = MFMA16(wf0, wxb0, acc2[1][tt]);
                acc2[0][tt] = MFMA16(wf1, wxa1, acc2[0][tt]);
                acc2[1][tt] = MFMA16(wf1, wxb1, acc2[1][tt]);
            }
        }
#pragma unroll
        for (int sh = 0; sh < 2; ++sh) {
            h2f[0][2 * th + sh] = packrelu(acc2[0], sh);
            h2f[1][2 * th + sh] = packrelu(acc2[1], sh);
        }
    }

    // ---- L1b: h2[128] -> h3[128]  (t split) ------------------------------
    bf16x8 h3f[2][4];
#pragma unroll
    for (int th = 0; th < 2; ++th) {
        f32x4 acc3[2][4];
#pragma unroll
        for (int tt = 0; tt < 4; ++tt) {
            f32x4 bv = *(const f32x4*)(wsb + BOFF_FC1B + 16 * (4 * th + tt) + 4 * gq);
            acc3[0][tt] = bv; acc3[1][tt] = bv;
        }
#pragma unroll
        for (int s = 0; s < 4; ++s) {
#pragma unroll
            for (int tt = 0; tt < 4; ++tt) {
                bf16x8 wf = Wfc1b[((4 * th + tt) * 4 + s) * 64 + lane];
                acc3[0][tt] = MFMA16(wf, h2f[0][s], acc3[0][tt]);
                acc3[1][tt] = MFMA16(wf, h2f[1][s], acc3[1][tt]);
            }
        }
#pragma unroll
        for (int sh = 0; sh < 2; ++sh) {
            h3f[0][2 * th + sh] = packrelu(acc3[0], sh);
            h3f[1][2 * th + sh] = packrelu(acc3[1], sh);
        }
    }

    // prefetch h0 (bf16 frags) and c0 (fp32) -- used 3 layers from now
    bf16x8 h0fa = ld8f(h0 + row0 * 32 + 8 * gq);
    bf16x8 h0fb = ld8f(h0 + row1 * 32 + 8 * gq);
    f32x4 c0r[2][2];
#pragma unroll
    for (int t2 = 0; t2 < 2; ++t2) {
        c0r[0][t2] = *(const f32x4*)(c0 + row0 * 32 + 16 * t2 + 4 * gq);
        c0r[1][t2] = *(const f32x4*)(c0 + row1 * 32 + 16 * t2 + 4 * gq);
    }

    // ---- L1c: [h3, w_game] -> h4[64]  (w_game folded into bias) ----------
    bf16x8 h4f[2][2];
    {
        f32x4 acc4[2][4];
#pragma unroll
        for (int t = 0; t < 4; ++t) {
            f32x4 bv = *(const f32x4*)(wsb + BOFF_FC1C + 16 * t + 4 * gq);
            acc4[0][t] = bv; acc4[1][t] = bv;
        }
#pragma unroll
        for (int s = 0; s < 4; ++s) {
#pragma unroll
            for (int t = 0; t < 4; ++t) {
                bf16x8 wf = Wfc1c[(t * 4 + s) * 64 + lane];
                acc4[0][t] = MFMA16(wf, h3f[0][s], acc4[0][t]);
                acc4[1][t] = MFMA16(wf, h3f[1][s], acc4[1][t]);
            }
        }
#pragma unroll
        for (int s = 0; s < 2; ++s) { h4f[0][s] = packrelu(acc4[0], s); h4f[1][s] = packrelu(acc4[1], s); }
    }

    // ---- L2: h4[64] -> h5[32] --------------------------------------------
    bf16x8 h5f[2];
    {
        f32x4 acc5[2][2];
#pragma unroll
        for (int t = 0; t < 2; ++t) {
            f32x4 bv = *(const f32x4*)(wsb + BOFF_FC2 + 16 * t + 4 * gq);
            acc5[0][t] = bv; acc5[1][t] = bv;
        }
#pragma unroll
        for (int s = 0; s < 2; ++s) {
#pragma unroll
            for (int t = 0; t < 2; ++t) {
                bf16x8 wf = Wfc2[(t * 2 + s) * 64 + lane];
                acc5[0][t] = MFMA16(wf, h4f[0][s], acc5[0][t]);
                acc5[1][t] = MFMA16(wf, h4f[1][s], acc5[1][t]);
            }
        }
        h5f[0] = packrelu(acc5[0], 0); h5f[1] = packrelu(acc5[1], 0);
    }

    // ---- L3: h5[32] -> h6[32] --------------------------------------------
    bf16x8 h6f[2];
    {
        f32x4 acc6[2][2];
#pragma unroll
        for (int t = 0; t < 2; ++t) {
            f32x4 bv = *(const f32x4*)(wsb + BOFF_FC3 + 16 * t + 4 * gq);
            acc6[0][t] = bv; acc6[1][t] = bv;
        }
#pragma unroll
        for (int t = 0; t < 2; ++t) {
            bf16x8 wf = Wfc3[t * 64 + lane];
            acc6[0][t] = MFMA16(wf, h5f[0], acc6[0][t]);
            acc6[1][t] = MFMA16(wf, h5f[1], acc6[1][t]);
        }
        h6f[0] = packrelu(acc6[0], 0); h6f[1] = packrelu(acc6[1], 0);
    }

    // ---- LSTM gates ------------------------------------------------------
    float hn[2][8];
    {
        f32x4 accg[2][8];
#pragma unroll
        for (int t = 0; t < 8; ++t) {
            f32x4 bv = *(const f32x4*)(wsb + BOFF_LSTM + 16 * t + 4 * gq);
            accg[0][t] = bv; accg[1][t] = bv;
        }
#pragma unroll
        for (int t = 0; t < 8; ++t) {
            bf16x8 wf = Wwih[t * 64 + lane];
            accg[0][t] = MFMA16(wf, h6f[0], accg[0][t]);
            accg[1][t] = MFMA16(wf, h6f[1], accg[1][t]);
        }
#pragma unroll
        for (int t = 0; t < 8; ++t) {
            bf16x8 wf = Wwhh[t * 64 + lane];
            accg[0][t] = MFMA16(wf, h0fa, accg[0][t]);
            accg[1][t] = MFMA16(wf, h0fb, accg[1][t]);
        }
        // gate tiles: i -> {0,1}, f -> {2,3}, g -> {4,5}, o -> {6,7}
#pragma unroll
        for (int m = 0; m < 2; ++m) {
#pragma unroll
            for (int t2 = 0; t2 < 2; ++t2) {
                f32x4 cc = c0r[m][t2];
#pragma unroll
                for (int r = 0; r < 4; ++r) {
                    float ig = accg[m][t2][r];
                    float fg = accg[m][2 + t2][r];
                    float gg = accg[m][4 + t2][r];
                    float og = accg[m][6 + t2][r];
                    float cn = sigm(fg) * cc[r] + sigm(ig) * tanh_(gg);
                    hn[m][t2 * 4 + r] = sigm(og) * tanh_(cn);
                }
            }
        }
    }
    bf16x8 hnf[2];
#pragma unroll
    for (int m = 0; m < 2; ++m)
#pragma unroll
        for (int j = 0; j < 8; ++j) hnf[m][j] = (__bf16)hn[m][j];

    // ---- L4: h_new[32] -> o1[32] -----------------------------------------
    f32x4 acco[2][2];
#pragma unroll
    for (int t = 0; t < 2; ++t) {
        f32x4 bv = *(const f32x4*)(wsb + BOFF_FC4 + 16 * t + 4 * gq);
        acco[0][t] = bv; acco[1][t] = bv;
    }
#pragma unroll
    for (int t = 0; t < 2; ++t) {
        bf16x8 wf = Wfc4[t * 64 + lane];
        acco[0][t] = MFMA16(wf, hnf[0], acco[0][t]);
        acco[1][t] = MFMA16(wf, hnf[1], acco[1][t]);
    }

    // ---- L5 + sigmoid ----------------------------------------------------
    f32x4 w5a = *(const f32x4*)(fc5w + 4 * gq);
    f32x4 w5b = *(const f32x4*)(fc5w + 16 + 4 * gq);
    float b5  = fc5b[0];
    float res[2];
#pragma unroll
    for (int m = 0; m < 2; ++m) {
        float p = 0.f;
#pragma unroll
        for (int r = 0; r < 4; ++r) {
            p += fmaxf(acco[m][0][r], 0.f) * w5a[r];
            p += fmaxf(acco[m][1][r], 0.f) * w5b[r];
        }
        p += __shfl_xor(p, 16);
        p += __shfl_xor(p, 32);
        res[m] = sigm(p + b5);
    }
    if (lane < 16) {
        out[rowbase + lane]      = res[0];
        out[rowbase + 16 + lane] = res[1];
    }
}

// ---------------------------------------------------------------------------
extern "C" void kernel_launch(void* const* d_in, const int* in_sizes, int n_in,
                              void* d_out, int out_size, void* d_ws, size_t ws_size,
                              hipStream_t stream) {
    const float* x     = (const float*)d_in[0];
    const float* w     = (const float*)d_in[1];
    const float* h0    = (const float*)d_in[2];
    const float* c0    = (const float*)d_in[3];
    const float* fc1w  = (const float*)d_in[4];
    const float* fc1b  = (const float*)d_in[5];
    const float* fc1aw = (const float*)d_in[6];
    const float* fc1ab = (const float*)d_in[7];
    const float* fc1bw = (const float*)d_in[8];
    const float* fc1bb = (const float*)d_in[9];
    const float* wgame = (const float*)d_in[10];
    const float* fc1cw = (const float*)d_in[11];
    const float* fc1cb = (const float*)d_in[12];
    const float* fc2w  = (const float*)d_in[13];
    const float* fc2b  = (const float*)d_in[14];
    const float* fc3w  = (const float*)d_in[15];
    const float* fc3b  = (const float*)d_in[16];
    const float* wih   = (const float*)d_in[17];
    const float* whh   = (const float*)d_in[18];
    const float* bih   = (const float*)d_in[19];
    const float* bhh   = (const float*)d_in[20];
    const float* fc4w  = (const float*)d_in[21];
    const float* fc4b  = (const float*)d_in[22];
    const float* fc5w  = (const float*)d_in[23];
    const float* fc5b  = (const float*)d_in[24];

    __bf16* wsw = (__bf16*)d_ws;
    float*  wsb = (float*)((char*)d_ws + WTOT * sizeof(__bf16));
    (void)ws_size; (void)n_in; (void)out_size;

    const int Btot = in_sizes[0] / 256;   // 131072 rows

    prep_kernel<<<(WTOT + BTOT + 255) / 256, 256, 0, stream>>>(
        fc1w, fc1b, fc1aw, fc1ab, fc1bw, fc1bb, wgame, fc1cw, fc1cb,
        fc2w, fc2b, fc3w, fc3b, wih, whh, bih, bhh, fc4w, fc4b, wsw, wsb);

    fused_mlp_lstm<<<Btot / 512, 1024, 0, stream>>>(
        x, w, h0, c0, fc5w, fc5b, wsw, wsb, (float*)d_out);
}